// Round 9
// baseline (294.352 us; speedup 1.0000x reference)
//
#include <hip/hip_runtime.h>
#include <math.h>

#define N_NODES 2000
#define N_EDGES 32000
#define BB 16
#define TT 20
#define NG (BB*TT)      // 320 graphs
#define OUTF 8
#define HID 24
#define FC_OUTD 160
#define FCC_OUTD 20

// ws layout (bytes)
#define WS_PACK   0         // u32[32000]: src | dst<<16   (128000 B)
#define WS_FEATS  131072    // float[NG*OUTF]
#define WS_M      141312    // float[480]
#define WS_B2     143232    // float[20]

// ---------- builder: pack src|dst (+ extra block: fused fcc@fc projection) ----------

__global__ __launch_bounds__(1024) void build_pack(
    const int* __restrict__ src, const int* __restrict__ dst,
    unsigned* __restrict__ pack,
    const float* __restrict__ fc_w, const float* __restrict__ fc_b,
    const float* __restrict__ fcc_w, const float* __restrict__ fcc_b,
    float* __restrict__ Mout, float* __restrict__ b2out)
{
    const int tid = threadIdx.x;
    if (blockIdx.x == 32) {   // prep block: M = fcc_w @ fc_w ; b2 = fcc_b + fcc_w @ fc_b
        if (tid < FCC_OUTD * HID) {
            const int j = tid / HID, h = tid % HID;
            float acc = 0.f;
#pragma unroll 4
            for (int m = 0; m < FC_OUTD; ++m)
                acc += fcc_w[j * FC_OUTD + m] * fc_w[m * HID + h];
            Mout[tid] = acc;
        } else if (tid < FCC_OUTD * HID + FCC_OUTD) {
            const int j = tid - FCC_OUTD * HID;
            float acc = fcc_b[j];
#pragma unroll 4
            for (int m = 0; m < FC_OUTD; ++m)
                acc += fcc_w[j * FC_OUTD + m] * fc_b[m];
            b2out[j] = acc;
        }
        return;
    }
    const int e = blockIdx.x * 1024 + tid;
    if (e < N_EDGES)
        pack[e] = (unsigned)src[e] | ((unsigned)dst[e] << 16);
}

// ---- GAT: 1 block (512 thr) per graph; register-prefetched edges + ds_add_f32 ----

__global__ __launch_bounds__(512) void gat_atomic(
    const float* __restrict__ x, const float* __restrict__ edge_w,
    const unsigned* __restrict__ pack,
    const float* __restrict__ W_node, const float* __restrict__ W_edge,
    const float* __restrict__ attn_l, const float* __restrict__ attn_e,
    const float* __restrict__ attn_r, const float* __restrict__ gat_b,
    float* __restrict__ feats)
{
    __shared__ float xs[N_NODES];                       // 8 KB
    __shared__ float aden[N_NODES], at1[N_NODES], at2[N_NODES];   // 24 KB
    __shared__ double wr1[8], wr2[8];

    const int g   = blockIdx.x;
    const int tid = threadIdx.x;

    // rank-1 projections collapse to 3 scalars
    float cl = 0.f, ce = 0.f, cr = 0.f;
#pragma unroll
    for (int k = 0; k < OUTF; ++k) {
        cl += W_node[k] * attn_l[k];
        cr += W_node[k] * attn_r[k];
        ce += W_edge[k] * attn_e[k];
    }

    const float* xg = x + (size_t)g * N_NODES;
    const float* wg = edge_w + (size_t)g * N_EDGES;

    {
        const float4* xg4 = (const float4*)xg;
        for (int i = tid; i < N_NODES / 4; i += 512) ((float4*)xs)[i] = xg4[i];
        for (int i = tid; i < N_NODES; i += 512) { aden[i] = 0.f; at1[i] = 0.f; at2[i] = 0.f; }
    }

    // ---- issue ALL edge loads for this thread into registers (fully static unroll) ----
    // 16 chunks of int4/float4: c = tid + k*512, k = 0..15; chunk 15 only for tid < 320.
    const int4*   pk4 = (const int4*)pack;
    const float4* wg4 = (const float4*)wg;
    int4   pA[8], pB[8];
    float4 wA[8], wB[8];
#pragma unroll
    for (int k = 0; k < 8; ++k) {
        const int c = tid + k * 512;
        pA[k] = pk4[c];
        wA[k] = wg4[c];
    }
#pragma unroll
    for (int k = 0; k < 8; ++k) {
        const int c = tid + (k + 8) * 512;
        const bool ok = (k < 7) || (tid < 320);
        if (ok) { pB[k] = pk4[c]; wB[k] = wg4[c]; }
    }

    __syncthreads();   // xs/accumulators ready (loads above are independent of LDS)

#define EDGE(mv, wv)                                              \
    {                                                             \
        const int   s   = (int)((mv) & 0xffffu);                  \
        const int   d   = (int)((mv) >> 16);                      \
        const float w   = (wv);                                   \
        const float xsv = xs[s];                                  \
        const float xdv = xs[d];                                  \
        float ev = cl * xsv + ce * w + cr * xdv;                  \
        ev = fmaxf(ev, 0.2f * ev);                                \
        const float num = __expf(ev);                             \
        unsafeAtomicAdd(&aden[d], num);                           \
        unsafeAtomicAdd(&at1[d],  num * xsv);                     \
        unsafeAtomicAdd(&at2[d],  num * w);                       \
    }

#pragma unroll
    for (int k = 0; k < 8; ++k) {
        EDGE((unsigned)pA[k].x, wA[k].x);
        EDGE((unsigned)pA[k].y, wA[k].y);
        EDGE((unsigned)pA[k].z, wA[k].z);
        EDGE((unsigned)pA[k].w, wA[k].w);
    }
#pragma unroll
    for (int k = 0; k < 8; ++k) {
        if ((k < 7) || (tid < 320)) {
            EDGE((unsigned)pB[k].x, wB[k].x);
            EDGE((unsigned)pB[k].y, wB[k].y);
            EDGE((unsigned)pB[k].z, wB[k].z);
            EDGE((unsigned)pB[k].w, wB[k].w);
        }
    }
#undef EDGE
    __syncthreads();

    // node pass: S1 = sum t1/den, S2 = sum t2/den (empty nodes contribute 0)
    double s1 = 0.0, s2 = 0.0;
    for (int n = tid; n < N_NODES; n += 512) {
        const float den = aden[n];
        if (den > 0.f) {
            s1 += (double)(at1[n] / den);
            s2 += (double)(at2[n] / den);
        }
    }
#pragma unroll
    for (int off = 32; off > 0; off >>= 1) {
        s1 += __shfl_down(s1, off, 64);
        s2 += __shfl_down(s2, off, 64);
    }
    const int wave = tid >> 6, lane = tid & 63;
    if (lane == 0) { wr1[wave] = s1; wr2[wave] = s2; }
    __syncthreads();
    if (tid == 0) {
        double a = 0.0, c = 0.0;
#pragma unroll
        for (int w = 0; w < 8; ++w) { a += wr1[w]; c += wr2[w]; }
#pragma unroll
        for (int k = 0; k < OUTF; ++k)
            feats[g * OUTF + k] = gat_b[k] +
                (float)((a * (double)W_node[k] + c * (double)W_edge[k]) / (double)N_NODES);
    }
}

// ---------------- head: 16 blocks (one per batch): LSTM + precomputed-M projection ----------------

__device__ __forceinline__ float fast_sigmoid(float v) {
    return 1.f / (1.f + __expf(-v));
}
__device__ __forceinline__ float fast_tanh(float v) {
    float t = __expf(2.f * v);
    return (t - 1.f) / (t + 1.f);
}

__global__ __launch_bounds__(128) void lstm_head(
    const float* __restrict__ feats, const float* __restrict__ Mw,
    const float* __restrict__ b2w,
    const float* __restrict__ w_ih, const float* __restrict__ w_hh,
    const float* __restrict__ b_ih, const float* __restrict__ b_hh,
    float* __restrict__ out)
{
    __shared__ float s_M[FCC_OUTD * HID];
    __shared__ float s_b2[FCC_OUTD];
    __shared__ float s_xt[TT * OUTF];
    __shared__ float s_bias[96];
    __shared__ float s_xg[TT * 96];
    __shared__ float s_g[96];
    __shared__ float s_h[HID], s_c[HID];
    __shared__ float s_hs[TT * HID];

    const int b   = blockIdx.x;
    const int tid = threadIdx.x;

    for (int i = tid; i < FCC_OUTD * HID; i += 128) s_M[i] = Mw[i];
    if (tid < FCC_OUTD) s_b2[tid] = b2w[tid];
    for (int i = tid; i < TT * OUTF; i += 128) s_xt[i] = feats[b * TT * OUTF + i];
    if (tid < 96) s_bias[tid] = b_ih[tid] + b_hh[tid];
    if (tid < HID) { s_h[tid] = 0.f; s_c[tid] = 0.f; }

    float rw_hh[HID];
    if (tid < 96) {
#pragma unroll
        for (int k = 0; k < HID; ++k) rw_hh[k] = w_hh[tid * HID + k];
    }
    __syncthreads();

    for (int u = tid; u < TT * 96; u += 128) {
        const int t = u / 96, j = u % 96;
        float acc = s_bias[j];
        const float* xt = &s_xt[t * OUTF];
#pragma unroll
        for (int k = 0; k < OUTF; ++k) acc += xt[k] * w_ih[j * OUTF + k];
        s_xg[u] = acc;
    }
    __syncthreads();

    for (int t = 0; t < TT; ++t) {
        if (tid < 96) {
            float acc = s_xg[t * 96 + tid];
#pragma unroll
            for (int k = 0; k < HID; ++k) acc += s_h[k] * rw_hh[k];
            s_g[tid] = acc;
        }
        __syncthreads();
        if (tid < HID) {
            const float i_ = fast_sigmoid(s_g[tid]);
            const float f_ = fast_sigmoid(s_g[24 + tid]);
            const float g_ = fast_tanh(s_g[48 + tid]);
            const float o_ = fast_sigmoid(s_g[72 + tid]);
            const float c = f_ * s_c[tid] + i_ * g_;
            s_c[tid] = c;
            const float h = o_ * fast_tanh(c);
            s_h[tid] = h;
            s_hs[t * HID + tid] = h;
        }
        __syncthreads();
    }

    for (int u = tid; u < TT * FCC_OUTD; u += 128) {
        const int t = u / FCC_OUTD, j = u % FCC_OUTD;
        float acc = s_b2[j];
        const float* hr = &s_hs[t * HID];
#pragma unroll
        for (int h = 0; h < HID; ++h) acc += hr[h] * s_M[j * HID + h];
        out[(b * TT + t) * FCC_OUTD + j] = acc;
    }
}

extern "C" void kernel_launch(void* const* d_in, const int* in_sizes, int n_in,
                              void* d_out, int out_size, void* d_ws, size_t ws_size,
                              hipStream_t stream) {
    const float* x      = (const float*)d_in[0];
    const float* edge_w = (const float*)d_in[1];
    const int*   src    = (const int*)d_in[2];
    const int*   dst    = (const int*)d_in[3];
    const float* W_node = (const float*)d_in[4];
    const float* W_edge = (const float*)d_in[5];
    const float* attn_l = (const float*)d_in[6];
    const float* attn_e = (const float*)d_in[7];
    const float* attn_r = (const float*)d_in[8];
    const float* gat_b  = (const float*)d_in[9];
    const float* w_ih   = (const float*)d_in[10];
    const float* w_hh   = (const float*)d_in[11];
    const float* b_ih   = (const float*)d_in[12];
    const float* b_hh   = (const float*)d_in[13];
    const float* fc_w   = (const float*)d_in[14];
    const float* fc_b   = (const float*)d_in[15];
    const float* fcc_w  = (const float*)d_in[16];
    const float* fcc_b  = (const float*)d_in[17];

    char* ws = (char*)d_ws;
    unsigned* pack  = (unsigned*)(ws + WS_PACK);
    float*    feats = (float*)(ws + WS_FEATS);
    float*    Mw    = (float*)(ws + WS_M);
    float*    b2w   = (float*)(ws + WS_B2);
    float*    out   = (float*)d_out;

    build_pack<<<33, 1024, 0, stream>>>(src, dst, pack, fc_w, fc_b, fcc_w, fcc_b, Mw, b2w);
    gat_atomic<<<NG, 512, 0, stream>>>(x, edge_w, pack, W_node, W_edge,
                                       attn_l, attn_e, attn_r, gat_b, feats);
    lstm_head<<<BB, 128, 0, stream>>>(feats, Mw, b2w, w_ih, w_hh, b_ih, b_hh, out);
}

// Round 10
// 84.019 us; speedup vs baseline: 3.5034x; 3.5034x over previous
//
#include <hip/hip_runtime.h>
#include <hip/hip_fp16.h>
#include <math.h>

#define N_NODES 2000
#define N_EDGES 32000
#define BB 16
#define TT 20
#define NG (BB*TT)      // 320 graphs
#define OUTF 8
#define HID 24
#define FC_OUTD 160
#define FCC_OUTD 20
#define EPT 32
#define NTE (N_EDGES/EPT)   // 1000 edge-threads

// ws layout (bytes)
#define WS_CNT     0         // int[2048]: hist counts, reused as scatter cursor
#define WS_ROWPTR  8192      // int[2048]
#define WS_CSRPOS  16384     // u32[32000] (128000)
#define WS_META    147456    // u32[32000] tiled int4 [8][NTE][4] (128000)
#define WS_FEATS   278528    // float[NG*OUTF]
#define WS_M       288768    // float[480]
#define WS_B2      290688    // float[20]
#define WS_HTILE   294912    // __half[NB][32000] tiled [4][NTE][8]

// ---------------- builders ----------------

__global__ __launch_bounds__(256) void hist_kernel(const int* __restrict__ dst,
                                                   int* __restrict__ counts) {
    for (int e = blockIdx.x * 256 + threadIdx.x; e < N_EDGES; e += 16 * 256)
        atomicAdd(&counts[dst[e]], 1);
}

__global__ __launch_bounds__(1024) void scan_kernel(const int* __restrict__ counts,
                                                    int* __restrict__ row_ptr,
                                                    int* __restrict__ cursor) {
    __shared__ int a[2048], b[2048];
    const int tid = threadIdx.x;
    a[tid]        = (tid        < N_NODES) ? counts[tid]        : 0;
    a[tid + 1024] = (tid + 1024 < N_NODES) ? counts[tid + 1024] : 0;
    __syncthreads();
    int *s = a, *d = b;
    for (int off = 1; off < 2048; off <<= 1) {
        d[tid] = s[tid] + (tid >= off ? s[tid - off] : 0);
        const int j = tid + 1024;
        d[j] = s[j] + (j >= off ? s[j - off] : 0);
        __syncthreads();
        int* t = s; s = d; d = t;
    }
    if (tid == 0) row_ptr[0] = 0;
    for (int i = tid; i < N_NODES; i += 1024) {
        row_ptr[i + 1] = s[i];
        cursor[i] = 0;
    }
}

__global__ __launch_bounds__(1024) void scatter_kernel(
    const int* __restrict__ src, const int* __restrict__ dst,
    const int* __restrict__ row_ptr, int* __restrict__ cursor,
    unsigned* __restrict__ meta, unsigned* __restrict__ csr_pos,
    const float* __restrict__ fc_w, const float* __restrict__ fc_b,
    const float* __restrict__ fcc_w, const float* __restrict__ fcc_b,
    float* __restrict__ Mout, float* __restrict__ b2out)
{
    const int tid = threadIdx.x;
    if (blockIdx.x == 32) {    // prep block: M = fcc_w @ fc_w ; b2 = fcc_b + fcc_w @ fc_b
        if (tid < FCC_OUTD * HID) {
            const int j = tid / HID, h = tid % HID;
            float acc = 0.f;
#pragma unroll 4
            for (int m = 0; m < FC_OUTD; ++m)
                acc += fcc_w[j * FC_OUTD + m] * fc_w[m * HID + h];
            Mout[tid] = acc;
        } else if (tid < FCC_OUTD * HID + FCC_OUTD) {
            const int j = tid - FCC_OUTD * HID;
            float acc = fcc_b[j];
#pragma unroll 4
            for (int m = 0; m < FC_OUTD; ++m)
                acc += fcc_w[j * FC_OUTD + m] * fc_b[m];
            b2out[j] = acc;
        }
        return;
    }
    const int e = blockIdx.x * 1024 + tid;
    if (e >= N_EDGES) return;
    const int s = src[e], d = dst[e];
    const int rp  = row_ptr[d];
    const int pos = rp + atomicAdd(&cursor[d], 1);
    const unsigned fl = (pos == rp) ? 1u : 0u;
    meta[(((pos & 31) >> 2) * NTE + (pos >> 5)) * 4 + (pos & 3)] =
        (unsigned)s | ((unsigned)d << 11) | (fl << 22);
    csr_pos[e] = (unsigned)pos;
}

// ---- permute: per graph, edge_w -> fp16 CSR-tiled layout (coalesced in/out via LDS) ----

__global__ __launch_bounds__(1024) void permute_kernel(
    const float* __restrict__ edge_w, const unsigned* __restrict__ csr_pos,
    __half* __restrict__ htile, int base)
{
    __shared__ __half lw[N_EDGES];     // 64 KB
    const int g   = base + blockIdx.x;
    const int tid = threadIdx.x;
    const float4* ew4 = (const float4*)(edge_w + (size_t)g * N_EDGES);
    const uint4*  cp4 = (const uint4*)csr_pos;
#pragma unroll
    for (int k = 0; k < 8; ++k) {
        const int c = tid + k * 1024;
        if (c < N_EDGES / 4) {
            const float4 wv = ew4[c];
            const uint4  pv = cp4[c];
#define TOFF(p) ((((p) & 31u) >> 3) * (NTE*8) + ((p) >> 5) * 8 + ((p) & 7u))
            lw[TOFF(pv.x)] = __float2half(wv.x);
            lw[TOFF(pv.y)] = __float2half(wv.y);
            lw[TOFF(pv.z)] = __float2half(wv.z);
            lw[TOFF(pv.w)] = __float2half(wv.w);
#undef TOFF
        }
    }
    __syncthreads();
    uint4* outp = (uint4*)(htile + (size_t)blockIdx.x * N_EDGES);
    const uint4* lw4 = (const uint4*)lw;
#pragma unroll
    for (int k = 0; k < 4; ++k) {
        const int c = tid + k * 1024;
        if (c < 4000) outp[c] = lw4[c];
    }
}

// ---- GAT: register-segmented CSR reduction, no atomics, ~1.1 DS/edge ----

__global__ __launch_bounds__(1024) void gat_csr2(
    const float* __restrict__ x, const __half* __restrict__ htile,
    const int4* __restrict__ meta4,
    const float* __restrict__ W_node, const float* __restrict__ W_edge,
    const float* __restrict__ attn_l, const float* __restrict__ attn_e,
    const float* __restrict__ attn_r, const float* __restrict__ gat_b,
    float* __restrict__ feats, int base)
{
    __shared__ float xs[N_NODES];               // 8 KB
    __shared__ int   hn[NTE];                   // 4 KB
    __shared__ float hp0[NTE], hp1[NTE], hp2[NTE];  // 12 KB
    __shared__ double wr1[16], wr2[16];

    const int g   = base + blockIdx.x;
    const int tid = threadIdx.x;

    float cl = 0.f, ce = 0.f, cr = 0.f;
#pragma unroll
    for (int k = 0; k < OUTF; ++k) {
        cl += W_node[k] * attn_l[k];
        cr += W_node[k] * attn_r[k];
        ce += W_edge[k] * attn_e[k];
    }

    if (tid < N_NODES / 4)
        ((float4*)xs)[tid] = ((const float4*)(x + (size_t)g * N_NODES))[tid];
    __syncthreads();

    double s1 = 0.0, s2 = 0.0;
    float den = 0.f, t1 = 0.f, t2 = 0.f, xd = 0.f;
    int cur = -1, headdone = 0;

    if (tid < NTE) {
        const uint4* h4 = (const uint4*)(htile + (size_t)blockIdx.x * N_EDGES);
        int4  mA = meta4[tid], mB = meta4[NTE + tid];
        uint4 hA = h4[tid];

#define PROC(mval, wword, hsel, FIRST)                                        \
        {                                                                     \
            const unsigned mm = (unsigned)(mval);                             \
            const int s = (int)(mm & 2047u);                                  \
            const int d = (int)((mm >> 11) & 2047u);                          \
            __half_raw hr;                                                    \
            hr.x = (hsel) ? (unsigned short)((wword) >> 16)                   \
                          : (unsigned short)((wword) & 0xffffu);              \
            const float w = __half2float((__half)hr);                         \
            if (mm & (1u << 22)) {                                            \
                if (headdone) {                                               \
                    s1 += (double)(t1 / den); s2 += (double)(t2 / den);       \
                } else {                                                      \
                    hn[tid] = cur; hp0[tid] = den; hp1[tid] = t1;             \
                    hp2[tid] = t2; headdone = 1;                              \
                }                                                             \
                den = 0.f; t1 = 0.f; t2 = 0.f; cur = d; xd = xs[d];           \
            } else if (FIRST) { cur = d; xd = xs[d]; }                        \
            const float xsv = xs[s];                                          \
            float ev = cl * xsv + ce * w + cr * xd;                           \
            ev = fmaxf(ev, 0.2f * ev);                                        \
            const float num = __expf(ev);                                     \
            den += num; t1 = fmaf(num, xsv, t1); t2 = fmaf(num, w, t2);       \
        }

#pragma unroll
        for (int k8 = 0; k8 < 4; ++k8) {
            int4 mA_n, mB_n; uint4 hA_n;
            if (k8 < 3) {
                mA_n = meta4[(2 * k8 + 2) * NTE + tid];
                mB_n = meta4[(2 * k8 + 3) * NTE + tid];
                hA_n = h4[(k8 + 1) * NTE + tid];
            }
            PROC(mA.x, hA.x, 0, (k8 == 0));
            PROC(mA.y, hA.x, 1, false);
            PROC(mA.z, hA.y, 0, false);
            PROC(mA.w, hA.y, 1, false);
            PROC(mB.x, hA.z, 0, false);
            PROC(mB.y, hA.z, 1, false);
            PROC(mB.z, hA.w, 0, false);
            PROC(mB.w, hA.w, 1, false);
            if (k8 < 3) { mA = mA_n; mB = mB_n; hA = hA_n; }
        }
#undef PROC
        if (!headdone) { hn[tid] = cur; hp0[tid] = den; hp1[tid] = t1; hp2[tid] = t2; }
    }
    __syncthreads();

    if (tid < NTE && headdone) {      // owner stitches continuation partials
        int tn = tid + 1;
        while (tn < NTE && hn[tn] == cur) {
            den += hp0[tn]; t1 += hp1[tn]; t2 += hp2[tn]; ++tn;
        }
        s1 += (double)(t1 / den);
        s2 += (double)(t2 / den);
    }

#pragma unroll
    for (int off = 32; off > 0; off >>= 1) {
        s1 += __shfl_down(s1, off, 64);
        s2 += __shfl_down(s2, off, 64);
    }
    const int wave = tid >> 6, lane = tid & 63;
    if (lane == 0) { wr1[wave] = s1; wr2[wave] = s2; }
    __syncthreads();
    if (tid == 0) {
        double a = 0.0, c = 0.0;
#pragma unroll
        for (int w = 0; w < 16; ++w) { a += wr1[w]; c += wr2[w]; }
#pragma unroll
        for (int k = 0; k < OUTF; ++k)
            feats[g * OUTF + k] = gat_b[k] +
                (float)((a * (double)W_node[k] + c * (double)W_edge[k]) / (double)N_NODES);
    }
}

// ---------------- head: 16 blocks (one per batch): LSTM + precomputed-M ----------------

__device__ __forceinline__ float fast_sigmoid(float v) {
    return 1.f / (1.f + __expf(-v));
}
__device__ __forceinline__ float fast_tanh(float v) {
    float t = __expf(2.f * v);
    return (t - 1.f) / (t + 1.f);
}

__global__ __launch_bounds__(128) void lstm_head(
    const float* __restrict__ feats, const float* __restrict__ Mw,
    const float* __restrict__ b2w,
    const float* __restrict__ w_ih, const float* __restrict__ w_hh,
    const float* __restrict__ b_ih, const float* __restrict__ b_hh,
    float* __restrict__ out)
{
    __shared__ float s_M[FCC_OUTD * HID];
    __shared__ float s_b2[FCC_OUTD];
    __shared__ float s_xt[TT * OUTF];
    __shared__ float s_bias[96];
    __shared__ float s_xg[TT * 96];
    __shared__ float s_g[96];
    __shared__ float s_h[HID], s_c[HID];
    __shared__ float s_hs[TT * HID];

    const int b   = blockIdx.x;
    const int tid = threadIdx.x;

    for (int i = tid; i < FCC_OUTD * HID; i += 128) s_M[i] = Mw[i];
    if (tid < FCC_OUTD) s_b2[tid] = b2w[tid];
    for (int i = tid; i < TT * OUTF; i += 128) s_xt[i] = feats[b * TT * OUTF + i];
    if (tid < 96) s_bias[tid] = b_ih[tid] + b_hh[tid];
    if (tid < HID) { s_h[tid] = 0.f; s_c[tid] = 0.f; }

    float rw_hh[HID];
    if (tid < 96) {
#pragma unroll
        for (int k = 0; k < HID; ++k) rw_hh[k] = w_hh[tid * HID + k];
    }
    __syncthreads();

    for (int u = tid; u < TT * 96; u += 128) {
        const int t = u / 96, j = u % 96;
        float acc = s_bias[j];
        const float* xt = &s_xt[t * OUTF];
#pragma unroll
        for (int k = 0; k < OUTF; ++k) acc += xt[k] * w_ih[j * OUTF + k];
        s_xg[u] = acc;
    }
    __syncthreads();

    for (int t = 0; t < TT; ++t) {
        if (tid < 96) {
            float acc = s_xg[t * 96 + tid];
#pragma unroll
            for (int k = 0; k < HID; ++k) acc += s_h[k] * rw_hh[k];
            s_g[tid] = acc;
        }
        __syncthreads();
        if (tid < HID) {
            const float i_ = fast_sigmoid(s_g[tid]);
            const float f_ = fast_sigmoid(s_g[24 + tid]);
            const float g_ = fast_tanh(s_g[48 + tid]);
            const float o_ = fast_sigmoid(s_g[72 + tid]);
            const float c = f_ * s_c[tid] + i_ * g_;
            s_c[tid] = c;
            const float h = o_ * fast_tanh(c);
            s_h[tid] = h;
            s_hs[t * HID + tid] = h;
        }
        __syncthreads();
    }

    for (int u = tid; u < TT * FCC_OUTD; u += 128) {
        const int t = u / FCC_OUTD, j = u % FCC_OUTD;
        float acc = s_b2[j];
        const float* hr = &s_hs[t * HID];
#pragma unroll
        for (int h = 0; h < HID; ++h) acc += hr[h] * s_M[j * HID + h];
        out[(b * TT + t) * FCC_OUTD + j] = acc;
    }
}

extern "C" void kernel_launch(void* const* d_in, const int* in_sizes, int n_in,
                              void* d_out, int out_size, void* d_ws, size_t ws_size,
                              hipStream_t stream) {
    const float* x      = (const float*)d_in[0];
    const float* edge_w = (const float*)d_in[1];
    const int*   src    = (const int*)d_in[2];
    const int*   dst    = (const int*)d_in[3];
    const float* W_node = (const float*)d_in[4];
    const float* W_edge = (const float*)d_in[5];
    const float* attn_l = (const float*)d_in[6];
    const float* attn_e = (const float*)d_in[7];
    const float* attn_r = (const float*)d_in[8];
    const float* gat_b  = (const float*)d_in[9];
    const float* w_ih   = (const float*)d_in[10];
    const float* w_hh   = (const float*)d_in[11];
    const float* b_ih   = (const float*)d_in[12];
    const float* b_hh   = (const float*)d_in[13];
    const float* fc_w   = (const float*)d_in[14];
    const float* fc_b   = (const float*)d_in[15];
    const float* fcc_w  = (const float*)d_in[16];
    const float* fcc_b  = (const float*)d_in[17];

    char* ws = (char*)d_ws;
    int*      counts  = (int*)(ws + WS_CNT);
    int*      row_ptr = (int*)(ws + WS_ROWPTR);
    unsigned* csr_pos = (unsigned*)(ws + WS_CSRPOS);
    unsigned* meta    = (unsigned*)(ws + WS_META);
    float*    feats   = (float*)(ws + WS_FEATS);
    float*    Mw      = (float*)(ws + WS_M);
    float*    b2w     = (float*)(ws + WS_B2);
    __half*   htile   = (__half*)(ws + WS_HTILE);
    float*    out     = (float*)d_out;

    hipMemsetAsync(counts, 0, N_NODES * sizeof(int), stream);
    hist_kernel<<<16, 256, 0, stream>>>(dst, counts);
    scan_kernel<<<1, 1024, 0, stream>>>(counts, row_ptr, counts /*cursor reuse*/);
    scatter_kernel<<<33, 1024, 0, stream>>>(src, dst, row_ptr, counts, meta, csr_pos,
                                            fc_w, fc_b, fcc_w, fcc_b, Mw, b2w);

    // batch graphs through the htile scratch region (64 KB per graph)
    size_t avail = (ws_size > (size_t)WS_HTILE) ? ws_size - (size_t)WS_HTILE : 0;
    int NB = (int)(avail / (N_EDGES * sizeof(__half)));
    if (NB > NG) NB = NG;
    if (NB < 1) NB = 1;
    for (int base = 0; base < NG; base += NB) {
        const int n = (NG - base < NB) ? (NG - base) : NB;
        permute_kernel<<<n, 1024, 0, stream>>>(edge_w, csr_pos, htile, base);
        gat_csr2<<<n, 1024, 0, stream>>>(x, htile, (const int4*)meta,
                                         W_node, W_edge, attn_l, attn_e, attn_r,
                                         gat_b, feats, base);
    }
    lstm_head<<<BB, 128, 0, stream>>>(feats, Mw, b2w, w_ih, w_hh, b_ih, b_hh, out);
}